// Round 13
// baseline (383.153 us; speedup 1.0000x reference)
//
#include <hip/hip_runtime.h>
#include <math.h>

#define BB 8
#define NVV 2048
#define NPP 4096
#define DD 64
#define NQ (BB * NVV)     // 16384 vertex rows
#define QT (NQ / 16)      // 1024 query tiles

typedef __attribute__((ext_vector_type(8))) short short8;
typedef __attribute__((ext_vector_type(8))) unsigned short ushort8;
typedef __attribute__((ext_vector_type(4))) float f32x4;

// ws layout (float offsets), audited line-by-line:
// vm      @0        (16384)
// inv_vf_s@16384    (16384)   = 16384/norm
// inv_pf_s@32768    (32768)
// flow    @65536    (65536)
// sem     @131072   (pc1 region reused; 8 bytes, memset each iteration)
// vfh     @655360   (QT*1024 ushorts = 524288 floats)
// vfl     @1179648  (+524288)
// pfh     @1703936  (2048 tiles*1024 ushorts = 1048576 floats)
// pfl     @2752512  (+1048576)
// end     @3801088  floats = 14.5 MB

__device__ __forceinline__ unsigned short bf16rn(float x) {
  unsigned u = __float_as_uint(x);
  return (unsigned short)((u + 0x7FFFu + ((u >> 16) & 1u)) >> 16);
}
__device__ __forceinline__ float bf2f(unsigned short h) {
  return __uint_as_float(((unsigned)h) << 16);
}

// Branchless sorted-ascending top-8 insert: 7x v_med3_u32 + 1x max.
__device__ __forceinline__ void net8(unsigned* a, unsigned v) {
#pragma unroll
  for (int k = 0; k < 7; k++) {
    unsigned r;
    asm("v_med3_u32 %0, %1, %2, %3" : "=v"(r) : "v"(v), "v"(a[k]), "v"(a[k + 1]));
    a[k] = r;
  }
  a[7] = a[7] > v ? a[7] : v;
}

__device__ __forceinline__ float dot64(const float4* __restrict__ a,
                                       const float4* __restrict__ b) {
  float a0 = 0.f, a1 = 0.f, a2 = 0.f, a3 = 0.f;
#pragma unroll
  for (int c = 0; c < 16; c++) {
    float4 x = a[c], y = b[c];
    a0 = fmaf(x.x, y.x, a0);
    a1 = fmaf(x.y, y.y, a1);
    a2 = fmaf(x.z, y.z, a2);
    a3 = fmaf(x.w, y.w, a3);
  }
  return (a0 + a1) + (a2 + a3);
}

// sortable u32 from fp32: monotone bijection (total order preserved)
__device__ __forceinline__ unsigned fkey(float s) {
  unsigned u = __float_as_uint(s);
  return ((int)u < 0) ? ~u : (u | 0x80000000u);
}

// Device-scope grid barrier: monotonic counter, zeroed by host memset each
// iteration (stream-serialized). Capacity-guaranteed co-residency: grid=512,
// __launch_bounds__(256,4) -> >=4 blocks/CU -> capacity 1024 (2x margin).
// __threadfence() = agent-scope fence (L2 wb/inv) on both sides -- the same
// semantics kernel boundaries provided for the 3-kernel pipeline.
__device__ __forceinline__ void gridbar(unsigned* sem, unsigned target) {
  __syncthreads();
  __threadfence();
  if (threadIdx.x == 0) {
    atomicAdd(sem, 1u);
    while (atomicAdd(sem, 0u) < target) __builtin_amdgcn_s_sleep(8);
  }
  __syncthreads();
  __threadfence();
}

// wave-per-tile norm+normalize+bf16 hi/lo staging (R24 body, verbatim math)
__device__ __forceinline__ void stage_tile(const float* __restrict__ src, int tile,
                                           unsigned short* __restrict__ dh,
                                           unsigned short* __restrict__ dl,
                                           float* __restrict__ ginv, int lane) {
  int c = lane & 15, quad = (lane >> 4) & 3;
  int row = tile * 16 + c;
  const float* rp = src + (size_t)row * DD + quad * 8;
  float4 a0 = *(const float4*)(rp);
  float4 b0 = *(const float4*)(rp + 4);
  float4 a1 = *(const float4*)(rp + 32);
  float4 b1 = *(const float4*)(rp + 36);
  float xs[16] = {a0.x, a0.y, a0.z, a0.w, b0.x, b0.y, b0.z, b0.w,
                  a1.x, a1.y, a1.z, a1.w, b1.x, b1.y, b1.z, b1.w};
  float ss = 0.f;
#pragma unroll
  for (int j = 0; j < 16; j++) ss = fmaf(xs[j], xs[j], ss);
  ss += __shfl_xor(ss, 16, 64);
  ss += __shfl_xor(ss, 32, 64);   // all quads hold the row total
  float inv = 1.0f / fmaxf(sqrtf(ss), 1e-12f);
  if (quad == 0) ginv[row] = 16384.0f * inv;  // pow2 scale: exact ratio later
  ushort8 h, l;
  size_t s0 = (size_t)tile * 128 + lane;      // kk=0 slot
#pragma unroll
  for (int j = 0; j < 8; j++) {
    float xn = xs[j] * inv;
    unsigned short hj = bf16rn(xn);
    h[j] = hj;
    l[j] = bf16rn(xn - bf2f(hj));
  }
  *(ushort8*)(dh + s0 * 8) = h;
  *(ushort8*)(dl + s0 * 8) = l;
#pragma unroll
  for (int j = 0; j < 8; j++) {
    float xn = xs[8 + j] * inv;
    unsigned short hj = bf16rn(xn);
    h[j] = hj;
    l[j] = bf16rn(xn - bf2f(hj));
  }
  *(ushort8*)(dh + (s0 + 64) * 8) = h;      // kk=1 slot
  *(ushort8*)(dl + (s0 + 64) * 8) = l;
}

// R20 k_knn inner-loop machinery (kept verbatim)
#define LOADK(d0, d1, d2, d3, KH, KL, tile) do {            \
    size_t bo_ = (size_t)(tile) * 1024 + lane * 8;          \
    d0 = *(const short8*)((KH) + bo_);                      \
    d1 = *(const short8*)((KH) + bo_ + 512);                \
    d2 = *(const short8*)((KL) + bo_);                      \
    d3 = *(const short8*)((KL) + bo_ + 512);                \
  } while (0)

#define MFMA6(c_, h0_, h1_, l0_, l1_) do {                                  \
    c_ = __builtin_amdgcn_mfma_f32_16x16x32_bf16(h0_, qh0, c_, 0, 0, 0);    \
    c_ = __builtin_amdgcn_mfma_f32_16x16x32_bf16(h1_, qh1, c_, 0, 0, 0);    \
    c_ = __builtin_amdgcn_mfma_f32_16x16x32_bf16(h0_, ql0, c_, 0, 0, 0);    \
    c_ = __builtin_amdgcn_mfma_f32_16x16x32_bf16(h1_, ql1, c_, 0, 0, 0);    \
    c_ = __builtin_amdgcn_mfma_f32_16x16x32_bf16(l0_, qh0, c_, 0, 0, 0);    \
    c_ = __builtin_amdgcn_mfma_f32_16x16x32_bf16(l1_, qh1, c_, 0, 0, 0);    \
  } while (0)

#define COMP1(h0_, h1_, l0_, l1_, b16_) do {                                \
    f32x4 c_ = {0.f, 0.f, 0.f, 0.f};                                        \
    MFMA6(c_, h0_, h1_, l0_, l1_);                                          \
    unsigned u0_ = (unsigned)fmaxf(fmaf(c_[0], 520000.0f, 520000.0f), 0.0f);\
    net8(tvA, (u0_ << 12) | (unsigned)((b16_) + 0));                        \
    unsigned u1_ = (unsigned)fmaxf(fmaf(c_[1], 520000.0f, 520000.0f), 0.0f);\
    net8(tvA, (u1_ << 12) | (unsigned)((b16_) + 1));                        \
    unsigned u2_ = (unsigned)fmaxf(fmaf(c_[2], 520000.0f, 520000.0f), 0.0f);\
    net8(tvB, (u2_ << 12) | (unsigned)((b16_) + 2));                        \
    unsigned u3_ = (unsigned)fmaxf(fmaf(c_[3], 520000.0f, 520000.0f), 0.0f);\
    net8(tvB, (u3_ << 12) | (unsigned)((b16_) + 3));                        \
  } while (0)

#define COMP2(h0_, h1_, l0_, l1_, b16_, mp_) do {                           \
    float4 mv_ = *(const float4*)(mp_);                                     \
    f32x4 c_ = {0.f, 0.f, 0.f, 0.f};                                        \
    MFMA6(c_, h0_, h1_, l0_, l1_);                                          \
    unsigned u0_ = (unsigned)fmaxf(fmaf(c_[0], 520000.0f, 520000.0f), 0.0f);\
    unsigned p0_ = (u0_ << 12) | (unsigned)((b16_) + 0);                    \
    net8(tvA, (mv_.x >= 0.5f) ? p0_ : 0u);                                  \
    unsigned u1_ = (unsigned)fmaxf(fmaf(c_[1], 520000.0f, 520000.0f), 0.0f);\
    unsigned p1_ = (u1_ << 12) | (unsigned)((b16_) + 1);                    \
    net8(tvA, (mv_.y >= 0.5f) ? p1_ : 0u);                                  \
    unsigned u2_ = (unsigned)fmaxf(fmaf(c_[2], 520000.0f, 520000.0f), 0.0f);\
    unsigned p2_ = (u2_ << 12) | (unsigned)((b16_) + 2);                    \
    net8(tvB, (mv_.z >= 0.5f) ? p2_ : 0u);                                  \
    unsigned u3_ = (unsigned)fmaxf(fmaf(c_[3], 520000.0f, 520000.0f), 0.0f);\
    unsigned p3_ = (u3_ << 12) | (unsigned)((b16_) + 3);                    \
    net8(tvB, (mv_.w >= 0.5f) ? p3_ : 0u);                                  \
  } while (0)

// ===== R26: fully fused pipeline, one launch, two software grid barriers ====
// Phases: prep (XCD-pinned) | bar | knn x2 tiles + flow epilogue (R24 body,
// pc2 kept in LDS cand2 -- consumer is the same block) | bar | final x2.
// All arithmetic bit-identical to R24. Saves 2 dispatch boundaries
// (~10-15us each, R21->R23 differencing).
__global__ __launch_bounds__(256, 4)
void k_all(const float* __restrict__ vtx, const float* __restrict__ pts,
           const float* __restrict__ vf, const float* __restrict__ pf,
           const float* __restrict__ lg, float* __restrict__ out,
           float* __restrict__ vm, float* __restrict__ inv_vf_s,
           float* __restrict__ inv_pf_s, float* __restrict__ flow_ws,
           unsigned short* __restrict__ vfh, unsigned short* __restrict__ vfl,
           unsigned short* __restrict__ pfh, unsigned short* __restrict__ pfl,
           unsigned* __restrict__ sem) {
  __shared__ float smn[2], smx[2];
  __shared__ unsigned mg[2][2][16][8];   // 2KB
  __shared__ unsigned cand[16][16];      // 1KB (KNN1 cand, per tile)
  __shared__ unsigned cand2[2][16][16];  // 2KB (KNN2 cand, both tiles)

  int p = blockIdx.x;                 // 0..511
  int xcd = p & 7, idx = p >> 3;      // batch pin: batch == xcd; idx in [0,64)
  int batch = xcd;
  int t = (int)threadIdx.x;
  int w = t >> 6;                     // wave 0..3
  int ck = w >> 1, hf = w & 1;
  int lane = t & 63, col = lane & 15, quad = lane >> 4;

  // ================= phase 0: prep (XCD-pinned) =================
  // 4 pf tiles (wave-per-tile), 2 vf tiles (waves 0,1), vm by idx==0 waves 2,3
  stage_tile(pf, xcd * 256 + idx * 4 + w, pfh, pfl, inv_pf_s, lane);
  bool dovm = (idx == 0 && w >= 2);
  float vals[16];
  if (w < 2) stage_tile(vf, xcd * 128 + idx * 2 + w, vfh, vfl, inv_vf_s, lane);
  float mn = 1e30f, mx = -1e30f;
  if (dovm) {
    int t2 = t - 128;                 // 0..127, 16 elems each
#pragma unroll
    for (int i = 0; i < 16; i++) {
      float x = lg[batch * NVV + t2 + i * 128];
      float s = 1.0f / (1.0f + expf(-x));
      vals[i] = s;
      mn = fminf(mn, s);
      mx = fmaxf(mx, s);
    }
    for (int o = 32; o; o >>= 1) {
      mn = fminf(mn, __shfl_xor(mn, o, 64));
      mx = fmaxf(mx, __shfl_xor(mx, o, 64));
    }
    if (lane == 0) { smn[w - 2] = mn; smx[w - 2] = mx; }
  }
  __syncthreads();
  if (dovm) {
    int t2 = t - 128;
    float mnn = fminf(smn[0], smn[1]), mxx = fmaxf(smx[0], smx[1]);
    float range = mxx - mnn;
#pragma unroll
    for (int i = 0; i < 16; i++) {
      float v = (vals[i] - mnn) / range;
      int g = batch * NVV + t2 + i * 128;
      vm[g] = v;
      out[g * 4 + 3] = v;
    }
  }

  gridbar(sem, 512);   // staging + vm visible device-wide

  // ========= phase 1: KNN (A: pf, B: vf-masked) + flow epilogue, 2 tiles ====
#pragma unroll 1
  for (int qi = 0; qi < 2; qi++) {
    int qt_g = xcd * 128 + idx * 2 + qi;

    size_t ab = (size_t)qt_g * 1024 + lane * 8;
    short8 qh0 = *(const short8*)(vfh + ab);
    short8 qh1 = *(const short8*)(vfh + ab + 512);
    short8 ql0 = *(const short8*)(vfl + ab);
    short8 ql1 = *(const short8*)(vfl + ab + 512);
    asm volatile("" : "+a"(qh0), "+a"(qh1), "+a"(ql0), "+a"(ql1));

    unsigned tvA[8], tvB[8];

    // ---- phase A: KNN1 (keys = pf), 64 tiles/wave ----
#pragma unroll
    for (int k = 0; k < 8; k++) { tvA[k] = 0u; tvB[k] = 0u; }
    {
      int bt0 = batch * 256 + ck * 128 + hf * 64;
      int tb16 = (ck * 128 + hf * 64) * 16 + quad * 4;
      short8 ah0, ah1, al0, al1, bh0, bh1, bl0, bl1;
      LOADK(ah0, ah1, al0, al1, pfh, pfl, bt0);
#pragma unroll 1
      for (int kt = 0; kt < 62; kt += 2) {
        LOADK(bh0, bh1, bl0, bl1, pfh, pfl, bt0 + kt + 1);
        COMP1(ah0, ah1, al0, al1, tb16 + kt * 16);
        LOADK(ah0, ah1, al0, al1, pfh, pfl, bt0 + kt + 2);
        COMP1(bh0, bh1, bl0, bl1, tb16 + (kt + 1) * 16);
      }
      LOADK(bh0, bh1, bl0, bl1, pfh, pfl, bt0 + 63);
      COMP1(ah0, ah1, al0, al1, tb16 + 62 * 16);
      COMP1(bh0, bh1, bl0, bl1, tb16 + 63 * 16);
    }
#pragma unroll
    for (int k = 0; k < 8; k++) net8(tvA, tvB[k]);
#pragma unroll
    for (int m = 16; m <= 32; m <<= 1) {
      unsigned ov[8];
#pragma unroll
      for (int k = 0; k < 8; k++) ov[k] = (unsigned)__shfl_xor((int)tvA[k], m, 64);
#pragma unroll
      for (int k = 7; k >= 0; k--) net8(tvA, ov[k]);
    }
    if (hf == 1 && quad == 0) {
#pragma unroll
      for (int k = 0; k < 8; k++) mg[0][ck][col][k] = tvA[k];
    }
    __syncthreads();
    if (hf == 0 && quad == 0) {
#pragma unroll
      for (int k = 0; k < 8; k++) net8(tvA, mg[0][ck][col][k]);
#pragma unroll
      for (int k = 0; k < 8; k++)
        cand[col][ck * 8 + k] = tvA[k];
    }

    // ---- phase B: KNN2 (keys = vf, visible only), 32 tiles/wave ----
#pragma unroll
    for (int k = 0; k < 8; k++) { tvA[k] = 0u; tvB[k] = 0u; }
    {
      const float* mask = vm + batch * NVV;
      int bt0 = batch * 128 + ck * 64 + hf * 32;
      int tbase = ck * 64 + hf * 32;
      int tb16 = tbase * 16 + quad * 4;
      const float* mp0 = mask + tbase * 16 + quad * 4;
      short8 ah0, ah1, al0, al1, bh0, bh1, bl0, bl1;
      LOADK(ah0, ah1, al0, al1, vfh, vfl, bt0);
#pragma unroll 1
      for (int kt = 0; kt < 30; kt += 2) {
        LOADK(bh0, bh1, bl0, bl1, vfh, vfl, bt0 + kt + 1);
        COMP2(ah0, ah1, al0, al1, tb16 + kt * 16, mp0 + kt * 16);
        LOADK(ah0, ah1, al0, al1, vfh, vfl, bt0 + kt + 2);
        COMP2(bh0, bh1, bl0, bl1, tb16 + (kt + 1) * 16, mp0 + (kt + 1) * 16);
      }
      LOADK(bh0, bh1, bl0, bl1, vfh, vfl, bt0 + 31);
      COMP2(ah0, ah1, al0, al1, tb16 + 30 * 16, mp0 + 30 * 16);
      COMP2(bh0, bh1, bl0, bl1, tb16 + 31 * 16, mp0 + 31 * 16);
    }
#pragma unroll
    for (int k = 0; k < 8; k++) net8(tvA, tvB[k]);
#pragma unroll
    for (int m = 16; m <= 32; m <<= 1) {
      unsigned ov[8];
#pragma unroll
      for (int k = 0; k < 8; k++) ov[k] = (unsigned)__shfl_xor((int)tvA[k], m, 64);
#pragma unroll
      for (int k = 7; k >= 0; k--) net8(tvA, ov[k]);
    }
    if (hf == 1 && quad == 0) {
#pragma unroll
      for (int k = 0; k < 8; k++) mg[1][ck][col][k] = tvA[k];
    }
    __syncthreads();
    if (hf == 0 && quad == 0) {
#pragma unroll
      for (int k = 0; k < 8; k++) net8(tvA, mg[1][ck][col][k]);
#pragma unroll
      for (int k = 0; k < 8; k++)
        cand2[qi][col][ck * 8 + k] = tvA[k];   // stays in LDS: consumer = this block
    }
    __syncthreads();

    // ---- fused exact re-rank of 16 KNN1 candidates + flow (R21 body) ----
    {
      int qloc = t >> 4, c = t & 15;
      int q = qt_g * 16 + qloc;
      int base = lane & 48;

      unsigned pk = cand[qloc][c];
      int id = (int)(pk & 0xFFFu);
      int prow = batch * NPP + id;
      const float4* qp = (const float4*)(vf + (size_t)q * DD);
      float dotv = dot64(qp, (const float4*)(pf + (size_t)prow * DD));
      float s = dotv * inv_pf_s[prow];
      unsigned kb = fkey(s);

      int rank = 0;
#pragma unroll
      for (int i = 0; i < 16; i++) {
        unsigned ok = (unsigned)__shfl((int)kb, base + i, 64);
        int oid = __shfl(id, base + i, 64);
        rank += (ok > kb || (ok == kb && oid > id)) ? 1 : 0;
      }
      float wgt = (rank < 8) ? dotv : 0.0f;

      float ax = 0.f, ay = 0.f, az = 0.f, den = 0.f;
      if (wgt != 0.0f) {
        ax = (pts[prow * 3 + 0] - vtx[q * 3 + 0]) * wgt;
        ay = (pts[prow * 3 + 1] - vtx[q * 3 + 1]) * wgt;
        az = (pts[prow * 3 + 2] - vtx[q * 3 + 2]) * wgt;
        den = wgt;
      }
#pragma unroll
      for (int m = 1; m <= 8; m <<= 1) {
        ax += __shfl_xor(ax, m, 64);
        ay += __shfl_xor(ay, m, 64);
        az += __shfl_xor(az, m, 64);
        den += __shfl_xor(den, m, 64);
      }
      if (c == 0) {
        float fx = ax / den, fy = ay / den, fz = az / den;
        flow_ws[q * 4 + 0] = fx;
        flow_ws[q * 4 + 1] = fy;
        flow_ws[q * 4 + 2] = fz;
        out[q * 4 + 0] = fx;
        out[q * 4 + 1] = fy;
        out[q * 4 + 2] = fz;
      }
    }
    __syncthreads();
  }

  gridbar(sem, 1024);  // flow_ws visible device-wide

  // ========= phase 2: exact KNN2 re-rank + invisible interp, 2 tiles =======
#pragma unroll 1
  for (int qi = 0; qi < 2; qi++) {
    int lb = xcd * 128 + idx * 2 + qi;
    int qloc = t >> 4, c = t & 15;
    int q = lb * 16 + qloc;
    int base = lane & 48;
    bool act = vm[q] < 0.5f;          // uniform per 16-group

    unsigned pk = cand2[qi][qloc][c];
    bool valid = act && (pk > 0xFFFu);
    int id = (int)(pk & 0xFFFu);
    int krow = batch * NVV + id;
    float dotv = 0.f;
    unsigned kb = 0u;
    if (valid) {
      dotv = dot64((const float4*)(vf + (size_t)q * DD),
                   (const float4*)(vf + (size_t)krow * DD));
      kb = fkey(dotv * inv_vf_s[krow]);
    }

    int rank = 0;
#pragma unroll
    for (int i = 0; i < 16; i++) {
      unsigned ok = (unsigned)__shfl((int)kb, base + i, 64);
      int oid = __shfl(id, base + i, 64);
      rank += (ok > kb || (ok == kb && oid > id)) ? 1 : 0;
    }
    float wgt = (valid && rank < 8) ? dotv : 0.0f;

    float ax = 0.f, ay = 0.f, az = 0.f, den = 0.f;
    if (wgt != 0.0f) {
      ax = flow_ws[krow * 4 + 0] * wgt;
      ay = flow_ws[krow * 4 + 1] * wgt;
      az = flow_ws[krow * 4 + 2] * wgt;
      den = wgt;
    }
#pragma unroll
    for (int m = 1; m <= 8; m <<= 1) {
      ax += __shfl_xor(ax, m, 64);
      ay += __shfl_xor(ay, m, 64);
      az += __shfl_xor(az, m, 64);
      den += __shfl_xor(den, m, 64);
    }
    if (act && c == 0) {
      out[q * 4 + 0] = ax / den;
      out[q * 4 + 1] = ay / den;
      out[q * 4 + 2] = az / den;
    }
  }
}

extern "C" void kernel_launch(void* const* d_in, const int* in_sizes, int n_in,
                              void* d_out, int out_size, void* d_ws, size_t ws_size,
                              hipStream_t stream) {
  const float* vtx = (const float*)d_in[0];
  const float* pts = (const float*)d_in[1];
  const float* vf = (const float*)d_in[2];
  const float* pf = (const float*)d_in[3];
  const float* lg = (const float*)d_in[4];
  float* out = (float*)d_out;
  float* ws = (float*)d_ws;

  float* vm = ws;
  float* inv_vf_s = ws + 16384;
  float* inv_pf_s = ws + 32768;
  float* flow = ws + 65536;
  unsigned* sem = (unsigned*)(ws + 131072);                // pc1 region reused
  unsigned short* vfh = (unsigned short*)(ws + 655360);
  unsigned short* vfl = (unsigned short*)(ws + 1179648);   // +524288 floats
  unsigned short* pfh = (unsigned short*)(ws + 1703936);   // +524288
  unsigned short* pfl = (unsigned short*)(ws + 2752512);   // +1048576

  hipMemsetAsync(sem, 0, 8, stream);   // barrier counter, zeroed each replay
  k_all<<<512, 256, 0, stream>>>(vtx, pts, vf, pf, lg, out, vm, inv_vf_s,
                                 inv_pf_s, flow, vfh, vfl, pfh, pfl, sem);
}

// Round 14
// 158.056 us; speedup vs baseline: 2.4242x; 2.4242x over previous
//
#include <hip/hip_runtime.h>
#include <math.h>

#define BB 8
#define NVV 2048
#define NPP 4096
#define DD 64
#define NQ (BB * NVV)     // 16384 vertex rows
#define QT (NQ / 16)      // 1024 query tiles

typedef __attribute__((ext_vector_type(8))) short short8;
typedef __attribute__((ext_vector_type(8))) unsigned short ushort8;
typedef __attribute__((ext_vector_type(4))) float f32x4;

// ws layout (float offsets), audited line-by-line:
// vm      @0        (16384)
// inv_vf_s@16384    (16384)   = 16384/norm
// inv_pf_s@32768    (32768)
// flow    @65536    (65536)
// pc1     @131072   (unused since R23 fold; layout kept)
// pc2     @393216   (16*16384 uints = 262144)
// vfh     @655360   (QT*1024 ushorts = 524288 floats)
// vfl     @1179648  (+524288)
// pfh     @1703936  (2048 tiles*1024 ushorts = 1048576 floats)
// pfl     @2752512  (+1048576)
// end     @3801088  floats = 14.5 MB

__device__ __forceinline__ unsigned short bf16rn(float x) {
  unsigned u = __float_as_uint(x);
  return (unsigned short)((u + 0x7FFFu + ((u >> 16) & 1u)) >> 16);
}
__device__ __forceinline__ float bf2f(unsigned short h) {
  return __uint_as_float(((unsigned)h) << 16);
}

// Branchless sorted-ascending top-8 insert: 7x v_med3_u32 + 1x max.
__device__ __forceinline__ void net8(unsigned* a, unsigned v) {
#pragma unroll
  for (int k = 0; k < 7; k++) {
    unsigned r;
    asm("v_med3_u32 %0, %1, %2, %3" : "=v"(r) : "v"(v), "v"(a[k]), "v"(a[k + 1]));
    a[k] = r;
  }
  a[7] = a[7] > v ? a[7] : v;
}

// sortable u32 from fp32: monotone bijection (total order preserved)
__device__ __forceinline__ unsigned fkey(float s) {
  unsigned u = __float_as_uint(s);
  return ((int)u < 0) ? ~u : (u | 0x80000000u);
}

// ===== kernel 1: staging (blocks 0..767, XCD-pinned) + vm (768..775) =====
__global__ __launch_bounds__(256) void k_prep(const float* __restrict__ logits,
                                              const float* __restrict__ vf,
                                              const float* __restrict__ pf,
                                              float* __restrict__ vm,
                                              float* __restrict__ inv_vf_s,
                                              float* __restrict__ inv_pf_s,
                                              unsigned short* __restrict__ vfh,
                                              unsigned short* __restrict__ vfl,
                                              unsigned short* __restrict__ pfh,
                                              unsigned short* __restrict__ pfl,
                                              float* __restrict__ out) {
  int bid = blockIdx.x, t = threadIdx.x;
  if (bid >= 768) {
    int b = bid - 768;                 // batch b on XCD b
    __shared__ float smn[4], smx[4];
    float vals[8];
    float mn = 1e30f, mx = -1e30f;
#pragma unroll
    for (int i = 0; i < 8; i++) {
      float x = logits[b * NVV + t + i * 256];
      float s = 1.0f / (1.0f + expf(-x));
      vals[i] = s;
      mn = fminf(mn, s);
      mx = fmaxf(mx, s);
    }
    for (int o = 32; o; o >>= 1) {
      mn = fminf(mn, __shfl_xor(mn, o, 64));
      mx = fmaxf(mx, __shfl_xor(mx, o, 64));
    }
    int w = t >> 6;
    if ((t & 63) == 0) { smn[w] = mn; smx[w] = mx; }
    __syncthreads();
    mn = fminf(fminf(smn[0], smn[1]), fminf(smn[2], smn[3]));
    mx = fmaxf(fmaxf(smx[0], smx[1]), fmaxf(smx[2], smx[3]));
    float range = mx - mn;
#pragma unroll
    for (int i = 0; i < 8; i++) {
      float v = (vals[i] - mn) / range;
      int g = b * NVV + t + i * 256;
      vm[g] = v;
      out[g * 4 + 3] = v;
    }
  } else {
    // XCD-pinned staging: batch == bid&7
    int xcd = bid & 7, kk = bid >> 3;  // kk in [0,96)
    int wsel = t >> 6;
    int lane = t & 63, c = lane & 15, quad = (lane >> 4) & 3;
    const float* src;
    unsigned short *dh, *dl;
    float* ginv;
    int tile;
    if (kk < 32) {                     // 32 blocks x 4 waves = 128 vf tiles
      tile = xcd * 128 + kk * 4 + wsel;
      src = vf; dh = vfh; dl = vfl; ginv = inv_vf_s;
    } else {                           // 64 blocks x 4 waves = 256 pf tiles
      tile = xcd * 256 + (kk - 32) * 4 + wsel;
      src = pf; dh = pfh; dl = pfl; ginv = inv_pf_s;
    }
    int row = tile * 16 + c;
    const float* rp = src + (size_t)row * DD + quad * 8;
    float4 a0 = *(const float4*)(rp);
    float4 b0 = *(const float4*)(rp + 4);
    float4 a1 = *(const float4*)(rp + 32);
    float4 b1 = *(const float4*)(rp + 36);
    float xs[16] = {a0.x, a0.y, a0.z, a0.w, b0.x, b0.y, b0.z, b0.w,
                    a1.x, a1.y, a1.z, a1.w, b1.x, b1.y, b1.z, b1.w};
    float ss = 0.f;
#pragma unroll
    for (int j = 0; j < 16; j++) ss = fmaf(xs[j], xs[j], ss);
    ss += __shfl_xor(ss, 16, 64);
    ss += __shfl_xor(ss, 32, 64);   // all quads now hold the row total
    float inv = 1.0f / fmaxf(sqrtf(ss), 1e-12f);
    if (quad == 0) ginv[row] = 16384.0f * inv;  // pow2 scale: exact ratio later
    ushort8 h, l;
    size_t s0 = (size_t)tile * 128 + lane;      // kk=0 slot
#pragma unroll
    for (int j = 0; j < 8; j++) {
      float xn = xs[j] * inv;
      unsigned short hj = bf16rn(xn);
      h[j] = hj;
      l[j] = bf16rn(xn - bf2f(hj));
    }
    *(ushort8*)(dh + s0 * 8) = h;
    *(ushort8*)(dl + s0 * 8) = l;
#pragma unroll
    for (int j = 0; j < 8; j++) {
      float xn = xs[8 + j] * inv;
      unsigned short hj = bf16rn(xn);
      h[j] = hj;
      l[j] = bf16rn(xn - bf2f(hj));
    }
    *(ushort8*)(dh + (s0 + 64) * 8) = h;      // kk=1 slot
    *(ushort8*)(dl + (s0 + 64) * 8) = l;
  }
}

// R20 k_knn inner-loop machinery (kept verbatim)
#define LOADK(d0, d1, d2, d3, KH, KL, tile) do {            \
    size_t bo_ = (size_t)(tile) * 1024 + lane * 8;          \
    d0 = *(const short8*)((KH) + bo_);                      \
    d1 = *(const short8*)((KH) + bo_ + 512);                \
    d2 = *(const short8*)((KL) + bo_);                      \
    d3 = *(const short8*)((KL) + bo_ + 512);                \
  } while (0)

#define MFMA6(c_, h0_, h1_, l0_, l1_) do {                                  \
    c_ = __builtin_amdgcn_mfma_f32_16x16x32_bf16(h0_, qh0, c_, 0, 0, 0);    \
    c_ = __builtin_amdgcn_mfma_f32_16x16x32_bf16(h1_, qh1, c_, 0, 0, 0);    \
    c_ = __builtin_amdgcn_mfma_f32_16x16x32_bf16(h0_, ql0, c_, 0, 0, 0);    \
    c_ = __builtin_amdgcn_mfma_f32_16x16x32_bf16(h1_, ql1, c_, 0, 0, 0);    \
    c_ = __builtin_amdgcn_mfma_f32_16x16x32_bf16(l0_, qh0, c_, 0, 0, 0);    \
    c_ = __builtin_amdgcn_mfma_f32_16x16x32_bf16(l1_, qh1, c_, 0, 0, 0);    \
  } while (0)

#define COMP1(h0_, h1_, l0_, l1_, b16_) do {                                \
    f32x4 c_ = {0.f, 0.f, 0.f, 0.f};                                        \
    MFMA6(c_, h0_, h1_, l0_, l1_);                                          \
    unsigned u0_ = (unsigned)fmaxf(fmaf(c_[0], 520000.0f, 520000.0f), 0.0f);\
    net8(tvA, (u0_ << 12) | (unsigned)((b16_) + 0));                        \
    unsigned u1_ = (unsigned)fmaxf(fmaf(c_[1], 520000.0f, 520000.0f), 0.0f);\
    net8(tvA, (u1_ << 12) | (unsigned)((b16_) + 1));                        \
    unsigned u2_ = (unsigned)fmaxf(fmaf(c_[2], 520000.0f, 520000.0f), 0.0f);\
    net8(tvB, (u2_ << 12) | (unsigned)((b16_) + 2));                        \
    unsigned u3_ = (unsigned)fmaxf(fmaf(c_[3], 520000.0f, 520000.0f), 0.0f);\
    net8(tvB, (u3_ << 12) | (unsigned)((b16_) + 3));                        \
  } while (0)

#define COMP2(h0_, h1_, l0_, l1_, b16_, mp_) do {                           \
    float4 mv_ = *(const float4*)(mp_);                                     \
    f32x4 c_ = {0.f, 0.f, 0.f, 0.f};                                        \
    MFMA6(c_, h0_, h1_, l0_, l1_);                                          \
    unsigned u0_ = (unsigned)fmaxf(fmaf(c_[0], 520000.0f, 520000.0f), 0.0f);\
    unsigned p0_ = (u0_ << 12) | (unsigned)((b16_) + 0);                    \
    net8(tvA, (mv_.x >= 0.5f) ? p0_ : 0u);                                  \
    unsigned u1_ = (unsigned)fmaxf(fmaf(c_[1], 520000.0f, 520000.0f), 0.0f);\
    unsigned p1_ = (u1_ << 12) | (unsigned)((b16_) + 1);                    \
    net8(tvA, (mv_.y >= 0.5f) ? p1_ : 0u);                                  \
    unsigned u2_ = (unsigned)fmaxf(fmaf(c_[2], 520000.0f, 520000.0f), 0.0f);\
    unsigned p2_ = (u2_ << 12) | (unsigned)((b16_) + 2);                    \
    net8(tvB, (mv_.z >= 0.5f) ? p2_ : 0u);                                  \
    unsigned u3_ = (unsigned)fmaxf(fmaf(c_[3], 520000.0f, 520000.0f), 0.0f);\
    unsigned p3_ = (u3_ << 12) | (unsigned)((b16_) + 3);                    \
    net8(tvB, (mv_.w >= 0.5f) ? p3_ : 0u);                                  \
  } while (0)

// ===== kernel 2: MFMA KNN + fused exact KNN1 re-rank & flow =====
// R27: R26's software grid barrier refuted (330us: fence-forced L2
// writeback + atomic spin). Reverted to R24 3-kernel structure; this
// round fixes the epilogue's memory pattern instead: cooperative
// coalesced candidate-dot. Lane c of each 16-lane group holds q-dims
// [4c,4c+4) (1 float4, kills 16x q-row redundancy); 16 iterations each
// load a CONTIGUOUS 256B candidate-row segment across the group (full
// line utilization vs 16B/lane scatter), 4-step shfl_xor reduce, lane k
// keeps candidate k's dot. Rank-select/weights/write-out unchanged.
// (Summation order differs from dot64 -> near-tie swaps possible; weight
// deltas tiny, threshold headroom 12x.)
__global__ __launch_bounds__(256)
void k_knn(const unsigned short* __restrict__ vfh, const unsigned short* __restrict__ vfl,
           const unsigned short* __restrict__ pfh, const unsigned short* __restrict__ pfl,
           const float* __restrict__ vm, unsigned* __restrict__ pc2,
           const float* __restrict__ vf, const float* __restrict__ pf,
           const float* __restrict__ pts, const float* __restrict__ vtx,
           const float* __restrict__ inv_pf_s,
           float* __restrict__ flow_ws, float* __restrict__ out) {
  __shared__ unsigned mg[2][2][16][8];   // [section][ck][col][k]   2KB
  __shared__ unsigned cand[16][16];      // [q-in-tile][candidate]  1KB

  int p = blockIdx.x;                 // 0..1023
  int xcd = p & 7, j = p >> 3;        // batch pin: batch == xcd
  int qt_g = xcd * 128 + j;           // this block's query tile
  int batch = xcd;
  int w = (int)threadIdx.x >> 6;      // wave 0..3
  int ck = w >> 1, hf = w & 1;        // chunk, half within chunk
  int lane = threadIdx.x & 63, col = lane & 15, quad = lane >> 4;

  // query frags once per wave (serve both phases)
  size_t ab = (size_t)qt_g * 1024 + lane * 8;
  short8 qh0 = *(const short8*)(vfh + ab);
  short8 qh1 = *(const short8*)(vfh + ab + 512);
  short8 ql0 = *(const short8*)(vfl + ab);
  short8 ql1 = *(const short8*)(vfl + ab + 512);
  // Pin loop-invariant query frags in AGPRs: MFMA reads AGPR A/B natively.
  asm volatile("" : "+a"(qh0), "+a"(qh1), "+a"(ql0), "+a"(ql1));

  unsigned tvA[8], tvB[8];

  // ---------------- phase A: KNN1 (keys = pf), 64 tiles ----------------
#pragma unroll
  for (int k = 0; k < 8; k++) { tvA[k] = 0u; tvB[k] = 0u; }
  {
    int bt0 = batch * 256 + ck * 128 + hf * 64;
    int tb16 = (ck * 128 + hf * 64) * 16 + quad * 4;
    short8 ah0, ah1, al0, al1, bh0, bh1, bl0, bl1;
    LOADK(ah0, ah1, al0, al1, pfh, pfl, bt0);
#pragma unroll 1
    for (int kt = 0; kt < 62; kt += 2) {
      LOADK(bh0, bh1, bl0, bl1, pfh, pfl, bt0 + kt + 1);
      COMP1(ah0, ah1, al0, al1, tb16 + kt * 16);
      LOADK(ah0, ah1, al0, al1, pfh, pfl, bt0 + kt + 2);
      COMP1(bh0, bh1, bl0, bl1, tb16 + (kt + 1) * 16);
    }
    LOADK(bh0, bh1, bl0, bl1, pfh, pfl, bt0 + 63);
    COMP1(ah0, ah1, al0, al1, tb16 + 62 * 16);
    COMP1(bh0, bh1, bl0, bl1, tb16 + 63 * 16);
  }
  // exact union of the two chains
#pragma unroll
  for (int k = 0; k < 8; k++) net8(tvA, tvB[k]);
  // butterfly across quads (lane bits 4,5) -- all quads end identical
#pragma unroll
  for (int m = 16; m <= 32; m <<= 1) {
    unsigned ov[8];
#pragma unroll
    for (int k = 0; k < 8; k++) ov[k] = (unsigned)__shfl_xor((int)tvA[k], m, 64);
#pragma unroll
    for (int k = 7; k >= 0; k--) net8(tvA, ov[k]);
  }
  if (hf == 1 && quad == 0) {
#pragma unroll
    for (int k = 0; k < 8; k++) mg[0][ck][col][k] = tvA[k];
  }
  __syncthreads();
  if (hf == 0 && quad == 0) {
#pragma unroll
    for (int k = 0; k < 8; k++) net8(tvA, mg[0][ck][col][k]);
#pragma unroll
    for (int k = 0; k < 8; k++)
      cand[col][ck * 8 + k] = tvA[k];
  }

  // ---------------- phase B: KNN2 (keys = vf, visible only), 32 tiles ----
#pragma unroll
  for (int k = 0; k < 8; k++) { tvA[k] = 0u; tvB[k] = 0u; }
  {
    const float* mask = vm + batch * NVV;
    int bt0 = batch * 128 + ck * 64 + hf * 32;
    int tbase = ck * 64 + hf * 32;
    int tb16 = tbase * 16 + quad * 4;
    const float* mp0 = mask + tbase * 16 + quad * 4;
    short8 ah0, ah1, al0, al1, bh0, bh1, bl0, bl1;
    LOADK(ah0, ah1, al0, al1, vfh, vfl, bt0);
#pragma unroll 1
    for (int kt = 0; kt < 30; kt += 2) {
      LOADK(bh0, bh1, bl0, bl1, vfh, vfl, bt0 + kt + 1);
      COMP2(ah0, ah1, al0, al1, tb16 + kt * 16, mp0 + kt * 16);
      LOADK(ah0, ah1, al0, al1, vfh, vfl, bt0 + kt + 2);
      COMP2(bh0, bh1, bl0, bl1, tb16 + (kt + 1) * 16, mp0 + (kt + 1) * 16);
    }
    LOADK(bh0, bh1, bl0, bl1, vfh, vfl, bt0 + 31);
    COMP2(ah0, ah1, al0, al1, tb16 + 30 * 16, mp0 + 30 * 16);
    COMP2(bh0, bh1, bl0, bl1, tb16 + 31 * 16, mp0 + 31 * 16);
  }
#pragma unroll
  for (int k = 0; k < 8; k++) net8(tvA, tvB[k]);
#pragma unroll
  for (int m = 16; m <= 32; m <<= 1) {
    unsigned ov[8];
#pragma unroll
    for (int k = 0; k < 8; k++) ov[k] = (unsigned)__shfl_xor((int)tvA[k], m, 64);
#pragma unroll
    for (int k = 7; k >= 0; k--) net8(tvA, ov[k]);
  }
  if (hf == 1 && quad == 0) {
#pragma unroll
    for (int k = 0; k < 8; k++) mg[1][ck][col][k] = tvA[k];
  }
  __syncthreads();
  if (hf == 0 && quad == 0) {
#pragma unroll
    for (int k = 0; k < 8; k++) net8(tvA, mg[1][ck][col][k]);
    int q = qt_g * 16 + col;
#pragma unroll
    for (int k = 0; k < 8; k++)
      pc2[(size_t)(ck * 8 + k) * NQ + q] = tvA[k];
  }
  __syncthreads();   // cand[] writes (phase A) ordered before epilogue reads

  // ------- fused exact re-rank of 16 KNN1 candidates + flow (coalesced) -----
  {
    int t = (int)threadIdx.x;
    int qloc = t >> 4, c = t & 15;
    int q = qt_g * 16 + qloc;
    int base = lane & 48;               // 16-lane group start

    // lane c holds q dims [4c, 4c+4): coalesced 256B per group
    float4 qv = *(const float4*)(vf + (size_t)q * DD + 4 * c);
    unsigned pk = cand[qloc][c];
    int id = (int)(pk & 0xFFFu);
    float dotv = 0.f;
#pragma unroll
    for (int k = 0; k < 16; k++) {
      int idk = (int)(cand[qloc][k] & 0xFFFu);
      float4 yv = *(const float4*)(pf + (size_t)(batch * NPP + idk) * DD + 4 * c);
      float pp = fmaf(qv.x, yv.x, fmaf(qv.y, yv.y, fmaf(qv.z, yv.z, qv.w * yv.w)));
      pp += __shfl_xor(pp, 1, 64);
      pp += __shfl_xor(pp, 2, 64);
      pp += __shfl_xor(pp, 4, 64);
      pp += __shfl_xor(pp, 8, 64);    // all 16 lanes hold candidate k's dot
      if (c == k) dotv = pp;
    }
    int prow = batch * NPP + id;
    float s = dotv * inv_pf_s[prow];    // exact cosine * 2^14
    unsigned kb = fkey(s);

    int rank = 0;
#pragma unroll
    for (int i = 0; i < 16; i++) {
      unsigned ok = (unsigned)__shfl((int)kb, base + i, 64);
      int oid = __shfl(id, base + i, 64);
      rank += (ok > kb || (ok == kb && oid > id)) ? 1 : 0;
    }
    float wgt = (rank < 8) ? dotv : 0.0f;  // raw dot weight (vm[q] cancels)

    float ax = 0.f, ay = 0.f, az = 0.f, den = 0.f;
    if (wgt != 0.0f) {
      ax = (pts[prow * 3 + 0] - vtx[q * 3 + 0]) * wgt;
      ay = (pts[prow * 3 + 1] - vtx[q * 3 + 1]) * wgt;
      az = (pts[prow * 3 + 2] - vtx[q * 3 + 2]) * wgt;
      den = wgt;
    }
#pragma unroll
    for (int m = 1; m <= 8; m <<= 1) {
      ax += __shfl_xor(ax, m, 64);
      ay += __shfl_xor(ay, m, 64);
      az += __shfl_xor(az, m, 64);
      den += __shfl_xor(den, m, 64);
    }
    if (c == 0) {
      float fx = ax / den, fy = ay / den, fz = az / den;
      flow_ws[q * 4 + 0] = fx;
      flow_ws[q * 4 + 1] = fy;
      flow_ws[q * 4 + 2] = fz;
      out[q * 4 + 0] = fx;
      out[q * 4 + 1] = fy;
      out[q * 4 + 2] = fz;
    }
  }
}

// ===== kernel 3: exact re-rank of 16 KNN2 candidates + interpolate invisible =====
// R27: same cooperative coalesced candidate-dot as the k_knn epilogue.
// act/valid predicates are uniform per 16-group -> no divergence inside
// the reduce; all scattered loads guarded.
__global__ __launch_bounds__(256) void k_merge_final(const unsigned* __restrict__ pc,
                                                     const float* __restrict__ vf,
                                                     const float* __restrict__ vm,
                                                     const float* __restrict__ inv_vf_s,
                                                     const float* __restrict__ flow_ws,
                                                     float* __restrict__ out) {
  int p = blockIdx.x;
  int xcd = p & 7, jj = p >> 3;
  int lb = xcd * 128 + jj;            // batch == xcd
  int t = (int)threadIdx.x;
  int qloc = t >> 4, c = t & 15;
  int q = lb * 16 + qloc, batch = q >> 11;
  int lane = t & 63;
  int base = lane & 48;
  bool act = vm[q] < 0.5f;            // uniform per 16-group

  unsigned pk = 0u;
  float4 qv = {0.f, 0.f, 0.f, 0.f};
  if (act) {
    pk = pc[(size_t)c * NQ + q];
    qv = *(const float4*)(vf + (size_t)q * DD + 4 * c);  // coalesced per group
  }
  bool valid = pk > 0xFFFu;           // 0 = masked sentinel
  int id = (int)(pk & 0xFFFu);

  float dotv = 0.f;
#pragma unroll
  for (int k = 0; k < 16; k++) {
    unsigned pk_k = (unsigned)__shfl((int)pk, base + k, 64);
    float pp = 0.f;
    if (act && pk_k > 0xFFFu) {       // uniform within the 16-group
      int idk = (int)(pk_k & 0xFFFu);
      float4 yv = *(const float4*)(vf + (size_t)(batch * NVV + idk) * DD + 4 * c);
      pp = fmaf(qv.x, yv.x, fmaf(qv.y, yv.y, fmaf(qv.z, yv.z, qv.w * yv.w)));
    }
    pp += __shfl_xor(pp, 1, 64);
    pp += __shfl_xor(pp, 2, 64);
    pp += __shfl_xor(pp, 4, 64);
    pp += __shfl_xor(pp, 8, 64);
    if (c == k) dotv = pp;
  }
  unsigned kb = 0u;
  if (act && valid) kb = fkey(dotv * inv_vf_s[batch * NVV + id]);

  int rank = 0;
#pragma unroll
  for (int i = 0; i < 16; i++) {
    unsigned ok = (unsigned)__shfl((int)kb, base + i, 64);
    int oid = __shfl(id, base + i, 64);
    rank += (ok > kb || (ok == kb && oid > id)) ? 1 : 0;
  }
  float wgt = (act && valid && rank < 8) ? dotv : 0.0f;

  float ax = 0.f, ay = 0.f, az = 0.f, den = 0.f;
  if (wgt != 0.0f) {
    int krow = batch * NVV + id;
    ax = flow_ws[krow * 4 + 0] * wgt;
    ay = flow_ws[krow * 4 + 1] * wgt;
    az = flow_ws[krow * 4 + 2] * wgt;
    den = wgt;
  }
#pragma unroll
  for (int m = 1; m <= 8; m <<= 1) {
    ax += __shfl_xor(ax, m, 64);
    ay += __shfl_xor(ay, m, 64);
    az += __shfl_xor(az, m, 64);
    den += __shfl_xor(den, m, 64);
  }
  if (act && c == 0) {
    out[q * 4 + 0] = ax / den;
    out[q * 4 + 1] = ay / den;
    out[q * 4 + 2] = az / den;
  }
}

extern "C" void kernel_launch(void* const* d_in, const int* in_sizes, int n_in,
                              void* d_out, int out_size, void* d_ws, size_t ws_size,
                              hipStream_t stream) {
  const float* vtx = (const float*)d_in[0];
  const float* pts = (const float*)d_in[1];
  const float* vf = (const float*)d_in[2];
  const float* pf = (const float*)d_in[3];
  const float* lg = (const float*)d_in[4];
  float* out = (float*)d_out;
  float* ws = (float*)d_ws;

  float* vm = ws;
  float* inv_vf_s = ws + 16384;
  float* inv_pf_s = ws + 32768;
  float* flow = ws + 65536;
  unsigned* pc2 = (unsigned*)(ws + 393216);
  unsigned short* vfh = (unsigned short*)(ws + 655360);
  unsigned short* vfl = (unsigned short*)(ws + 1179648);   // +524288 floats
  unsigned short* pfh = (unsigned short*)(ws + 1703936);   // +524288
  unsigned short* pfl = (unsigned short*)(ws + 2752512);   // +1048576

  k_prep<<<768 + BB, 256, 0, stream>>>(lg, vf, pf, vm, inv_vf_s, inv_pf_s,
                                       vfh, vfl, pfh, pfl, out);
  k_knn<<<1024, 256, 0, stream>>>(vfh, vfl, pfh, pfl, vm, pc2,
                                  vf, pf, pts, vtx, inv_pf_s, flow, out);
  k_merge_final<<<NQ * 16 / 256, 256, 0, stream>>>(pc2, vf, vm, inv_vf_s,
                                                   flow, out);
}